// Round 5
// baseline (356.486 us; speedup 1.0000x reference)
//
#include <hip/hip_runtime.h>
#include <math.h>

// ---------------- problem constants ----------------
// B=2, K=19 -> BK=38 batches; M=1024 points; C=256 feat ch; NPOINT=NSAMPLE=128
#define NBK   38

// ---------------- workspace layout (bytes) ----------------
#define OFF_XC    0u          // [38][3][1024] f32        = 466944
#define OFF_NXYZ  466944u     // [38][128][3]  f32        = 58368
#define OFF_BIDX  525312u     // [38][128][128] i32       = 2490368
#define OFF_W1F   3015680u    // [38][1024][128] f32      = 19922944
#define OFF_PREP  22938624u   // 4096 f32
#define OFF_WT    22955008u   // 32768 f32: c1t (0), c2t (16384)
#define OFF_WF    23086080u   // 131072 shorts: w2/w3 A-frags (0..65535), w1feat A-frags (65536..)
#define OFF_CNT   23348224u   // [38][128] i32 ball counts = 19456

// ---------------- d_out layout (float offsets) ----------------
#define OUT_AGG   24320       // scores at 0: (2,19,128,5)
#define OUT_FEAT  38912       // agg: (2,19,128,3), feat: (2,19,128,128)

typedef short bf16x8 __attribute__((ext_vector_type(8)));   // 8 bf16 = 4 VGPR
typedef float f32x4  __attribute__((ext_vector_type(4)));
typedef int   v4i    __attribute__((ext_vector_type(4)));
typedef int   v2i    __attribute__((ext_vector_type(2)));

// exact IEEE fp32 squared distance, no FMA contraction, ((d0^2+d1^2)+d2^2)
__device__ __forceinline__ float dist2f(float a0, float a1, float a2,
                                        float b0, float b1, float b2) {
#pragma clang fp contract(off)
  float d0 = a0 - b0;
  float d1 = a1 - b1;
  float d2 = a2 - b2;
  return d0 * d0 + d1 * d1 + d2 * d2;
}

// 2-way bf16 split with round-to-nearest-even: v ~= hi + mid, residual <= 2^-18 |v|
// returns the two bf16 bit patterns in the LOW 16 bits of sh/sm.
__device__ __forceinline__ void split2rn(float v, unsigned& sh, unsigned& sm) {
  unsigned u = __float_as_uint(v);
  unsigned rh = (u + 0x7fffu + ((u >> 16) & 1u)) & 0xffff0000u;
  sh = rh >> 16;
  float r1 = v - __uint_as_float(rh);        // exact in fp32
  unsigned u1 = __float_as_uint(r1);
  unsigned rm = (u1 + 0x7fffu + ((u1 >> 16) & 1u)) & 0xffff0000u;
  sm = rm >> 16;
}

// ---------------- prep: fold BN constants ----------------
__global__ __launch_bounds__(256) void prep_kernel(
    const float* __restrict__ m1w, const float* __restrict__ m1g, const float* __restrict__ m1be,
    const float* __restrict__ m2b, const float* __restrict__ m2g, const float* __restrict__ m2be,
    const float* __restrict__ m3b, const float* __restrict__ m3g, const float* __restrict__ m3be,
    const float* __restrict__ c1b, const float* __restrict__ c1g, const float* __restrict__ c1be,
    const float* __restrict__ c2b, const float* __restrict__ c2g, const float* __restrict__ c2be,
    float* __restrict__ prep)
{
  int t = threadIdx.x;
  if (t < 128) {
    float inv = 1.0f / sqrtf(1.0f + 1e-5f);
    float a1 = m1g[t] * inv;
    prep[t] = a1;                      // alpha1 (used by w1f epilogue)
    float a2 = m2g[t] * inv;  prep[256 + t] = a2;  prep[384 + t] = fmaf(m2b[t], a2, m2be[t]);
    float a3 = m3g[t] * inv;  prep[512 + t] = a3;  prep[640 + t] = fmaf(m3b[t], a3, m3be[t]);
    float ac1 = c1g[t] * inv; prep[768 + t] = ac1; prep[896 + t] = fmaf(c1b[t], ac1, c1be[t]);
    float ac2 = c2g[t] * inv; prep[1024 + t] = ac2; prep[1152 + t] = fmaf(c2b[t], ac2, c2be[t]);
    // packed per-channel consts for h1 build: {wx0*a1, wx1*a1, wx2*a1, be1}
    prep[1280 + 4 * t + 0] = m1w[t * 259 + 0] * a1;
    prep[1280 + 4 * t + 1] = m1w[t * 259 + 1] * a1;
    prep[1280 + 4 * t + 2] = m1w[t * 259 + 2] * a1;
    prep[1280 + 4 * t + 3] = m1be[t];
  }
}

// ---------------- wsplit: pre-split weights into MFMA A-fragment layout ----------
__global__ __launch_bounds__(256) void wsplit_kernel(
    const float* __restrict__ m1w, const float* __restrict__ m2w,
    const float* __restrict__ m3w, const float* __restrict__ c1w,
    const float* __restrict__ c2w, short* __restrict__ Wf, float* __restrict__ wt)
{
  int idx = blockIdx.x * 256 + threadIdx.x;      // 0..16383 (64 blocks)
#pragma unroll
  for (int e = 0; e < 4; ++e) {
    int i = idx * 4 + e;                         // 0..65535
    if (i < 32768) {
      int c = i & 127, o = (i >> 7) & 127, l = i >> 14;
      float w = (l ? m3w : m2w)[o * 128 + c];
      unsigned sh, sm;
      split2rn(w, sh, sm);
      int ot = o >> 4, mm = o & 15, kk = c >> 5, q = (c & 31) >> 3, j = c & 7;
      int within = (q * 16 + mm) * 8 + j;
      Wf[(((l * 2 + 0) * 4 + kk) * 8 + ot) * 512 + within] = (short)sh;
      Wf[(((l * 2 + 1) * 4 + kk) * 8 + ot) * 512 + within] = (short)sm;
    } else {
      int jdx = i - 32768;
      int o = jdx >> 8, c = jdx & 255;
      float w = m1w[o * 259 + 3 + c];
      unsigned sh, sm;
      split2rn(w, sh, sm);
      int ot = o >> 4, mm = o & 15, kk = c >> 5, q = (c & 31) >> 3, j = c & 7;
      int within = (q * 16 + mm) * 8 + j;
      Wf[65536 + ((kk) * 8 + ot) * 512 + within] = (short)sh;
      Wf[65536 + ((8 + kk) * 8 + ot) * 512 + within] = (short)sm;
    }
  }
  {
    int i = idx;                                  // 0..16383, exactly one pass
    int c = i >> 7, o = i & 127;
    wt[i] = c1w[o * 128 + c];                     // c1t[c][o]
    wt[16384 + i] = c2w[o * 128 + c];             // c2t[c][o]
  }
}

// ---------------- FPS: 256 thr/batch, candidate-broadcast, 1 barrier/iter -------
// Wave winners publish {dist_bits, 1023-idx, x, y, z}; all threads pick best of 4.
__global__ __launch_bounds__(256) void fps_kernel(const float* __restrict__ xyz,
    float* __restrict__ xc, float* __restrict__ nxyz, float* __restrict__ agg)
{
  int bk = blockIdx.x, t = threadIdx.x;
  int b = bk / 19, k = bk % 19;
  int wave = t >> 6, lane = t & 63;
  __shared__ int scand[2][4][8];   // [parity][wave][{dbits, 1023-idx, x, y, z, pad..}]
  float x0[4], x1[4], x2[4], dist[4];
#pragma unroll
  for (int j = 0; j < 4; ++j) {
    int i = j * 256 + t;
    const float* src = xyz + ((size_t)((b * 1024 + i) * 19 + k)) * 3;
    x0[j] = src[0]; x1[j] = src[1]; x2[j] = src[2];
    xc[(bk * 3 + 0) * 1024 + i] = x0[j];
    xc[(bk * 3 + 1) * 1024 + i] = x1[j];
    xc[(bk * 3 + 2) * 1024 + i] = x2[j];
    dist[j] = 1e10f;
  }
  if (t == 0) {
#pragma unroll
    for (int w = 0; w < 4; ++w) {
      scand[0][w][0] = 0;
      scand[0][w][1] = 1023;                    // idx 0
      scand[0][w][2] = __float_as_int(x0[0]);
      scand[0][w][3] = __float_as_int(x1[0]);
      scand[0][w][4] = __float_as_int(x2[0]);
    }
  }
  __syncthreads();

  for (int it = 0; it < 128; ++it) {
    int pi = it & 1;
    // ---- pick best of 4 wave candidates (all threads, registers) ----
    v4i s0 = *(const v4i*)&scand[pi][0][0]; int z0 = scand[pi][0][4];
    v4i s1 = *(const v4i*)&scand[pi][1][0]; int z1 = scand[pi][1][4];
    v4i s2 = *(const v4i*)&scand[pi][2][0]; int z2 = scand[pi][2][4];
    v4i s3 = *(const v4i*)&scand[pi][3][0]; int z3 = scand[pi][3][4];
    unsigned long long k0 = ((unsigned long long)(unsigned)s0.x << 32) | (unsigned)s0.y;
    unsigned long long k1 = ((unsigned long long)(unsigned)s1.x << 32) | (unsigned)s1.y;
    unsigned long long k2 = ((unsigned long long)(unsigned)s2.x << 32) | (unsigned)s2.y;
    unsigned long long k3 = ((unsigned long long)(unsigned)s3.x << 32) | (unsigned)s3.y;
    if (k1 > k0) { k0 = k1; s0 = s1; z0 = z1; }
    if (k3 > k2) { k2 = k3; s2 = s3; z2 = z3; }
    if (k2 > k0) { k0 = k2; s0 = s2; z0 = z2; }
    float c0 = __int_as_float(s0.z);
    float c1 = __int_as_float(s0.w);
    float c2 = __int_as_float(z0);
    if (t < 3) {
      float cv = (t == 0) ? c0 : ((t == 1) ? c1 : c2);
      nxyz[(bk * 128 + it) * 3 + t] = cv;
      agg[(bk * 128 + it) * 3 + t]  = cv;
    }
    // ---- update dists, wave f32-max reduce ----
#pragma unroll
    for (int j = 0; j < 4; ++j) {
      float d = dist2f(x0[j], x1[j], x2[j], c0, c1, c2);
      dist[j] = fminf(dist[j], d);
    }
    float dmax = fmaxf(fmaxf(dist[0], dist[1]), fmaxf(dist[2], dist[3]));
#pragma unroll
    for (int off = 1; off <= 32; off <<= 1)
      dmax = fmaxf(dmax, __shfl_xor(dmax, off));
    // ---- exact first-max index: per-j ballots, j ascending ----
    unsigned long long b0 = __ballot(dist[0] == dmax);
    unsigned long long b1 = __ballot(dist[1] == dmax);
    unsigned long long b2 = __ballot(dist[2] == dmax);
    unsigned long long b3 = __ballot(dist[3] == dmax);
    int idx;
    if (b0)      idx =       (wave << 6) + __builtin_ctzll(b0);
    else if (b1) idx = 256 + (wave << 6) + __builtin_ctzll(b1);
    else if (b2) idx = 512 + (wave << 6) + __builtin_ctzll(b2);
    else         idx = 768 + (wave << 6) + __builtin_ctzll(b3);
    if (lane == (idx & 63)) {
      int j = idx >> 8;
      float w0 = (j == 0) ? x0[0] : (j == 1) ? x0[1] : (j == 2) ? x0[2] : x0[3];
      float w1 = (j == 0) ? x1[0] : (j == 1) ? x1[1] : (j == 2) ? x1[2] : x1[3];
      float w2 = (j == 0) ? x2[0] : (j == 1) ? x2[1] : (j == 2) ? x2[2] : x2[3];
      int* slot = &scand[pi ^ 1][wave][0];
      slot[0] = __float_as_int(dmax);
      slot[1] = 1023 - idx;
      slot[2] = __float_as_int(w0);
      slot[3] = __float_as_int(w1);
      slot[4] = __float_as_int(w2);
    }
    __syncthreads();
  }
}

// ---------------- ball query: one wave per (bk,p); also emits count ------------
__global__ __launch_bounds__(64) void ball_kernel(const float* __restrict__ xc,
    const float* __restrict__ nxyz, int* __restrict__ bidx, int* __restrict__ counts)
{
  int gb = blockIdx.x;
  int bk = gb >> 7, p = gb & 127, lane = threadIdx.x;
  const float* x0 = xc + (bk * 3 + 0) * 1024;
  const float* x1 = xc + (bk * 3 + 1) * 1024;
  const float* x2 = xc + (bk * 3 + 2) * 1024;
  float c0 = nxyz[(bk * 128 + p) * 3 + 0];
  float c1 = nxyz[(bk * 128 + p) * 3 + 1];
  float c2 = nxyz[(bk * 128 + p) * 3 + 2];
  int* out = bidx + ((size_t)gb) * 128;
  int count = 0, first = 0;
  bool got = false;
  for (int ch = 0; ch < 16 && count < 128; ++ch) {
    int m = (ch << 6) + lane;
    float d = dist2f(x0[m], x1[m], x2[m], c0, c1, c2);
    bool flag = d < 0.0225f;                 // strict fp32 compare, RADIUS^2
    unsigned long long mask = __ballot(flag);
    if (!got && mask) { first = (ch << 6) + __builtin_ctzll(mask); got = true; }
    int pos = count + (int)__popcll(mask & ((1ull << lane) - 1ull));
    if (flag && pos < 128) out[pos] = m;
    count += (int)__popcll(mask);
  }
  for (int j = count + lane; j < 128; j += 64) out[j] = first;
  if (lane == 0) counts[gb] = count > 128 ? 128 : count;
}

// ---------------- W1f: per-bk layer-1 feature GEMM via split2 MFMA ----------------
__global__ __launch_bounds__(256, 2) void w1f_kernel(
    const float* __restrict__ feats, const float* __restrict__ m1b,
    const float* __restrict__ prep, const short* __restrict__ Wf,
    float* __restrict__ W1f)
{
  __shared__ __align__(16) short ffrag[16384];    // 32KB: [sp2][kkl2][st8]*512
  int blk = blockIdx.x;
  int bk = blk >> 3, m0 = (blk & 7) << 7;
  int b = bk / 19, k = bk % 19;
  int t = threadIdx.x;
  int wave = t >> 6, lane = t & 63;
  int quad = lane >> 4, nl = lane & 15;
  int mloc = t & 127, chalf = t >> 7;
  int st_w = mloc >> 4, sl_w = mloc & 15;
  const float* fbase = feats + ((size_t)(b * 4864 + k)) * 1024 + m0 + mloc;
  const short* WA = Wf + 65536;

  f32x4 acc[2][8];
#pragma unroll
  for (int oi = 0; oi < 2; ++oi)
#pragma unroll
    for (int st = 0; st < 8; ++st) acc[oi][st] = (f32x4){0.f, 0.f, 0.f, 0.f};

  for (int ch = 0; ch < 4; ++ch) {
    int cbase = ch * 64 + chalf * 32;
#pragma unroll
    for (int g = 0; g < 4; ++g) {
      float v[8];
#pragma unroll
      for (int j = 0; j < 8; ++j)
        v[j] = fbase[(size_t)(cbase + g * 8 + j) * 19456];
      unsigned sh[8], sm[8];
#pragma unroll
      for (int j = 0; j < 8; ++j) split2rn(v[j], sh[j], sm[j]);
      int base = chalf * 4096 + st_w * 512 + (g * 16 + sl_w) * 8;
      v4i ph = {(int)(sh[0] | (sh[1] << 16)), (int)(sh[2] | (sh[3] << 16)),
                (int)(sh[4] | (sh[5] << 16)), (int)(sh[6] | (sh[7] << 16))};
      *(v4i*)&ffrag[base] = ph;
      v4i pm = {(int)(sm[0] | (sm[1] << 16)), (int)(sm[2] | (sm[3] << 16)),
                (int)(sm[4] | (sm[5] << 16)), (int)(sm[6] | (sm[7] << 16))};
      *(v4i*)&ffrag[base + 8192] = pm;
    }
    __syncthreads();
#pragma unroll
    for (int kkl = 0; kkl < 2; ++kkl) {
      int kk = ch * 2 + kkl;
      bf16x8 a[2][2];
#pragma unroll
      for (int oi = 0; oi < 2; ++oi)
#pragma unroll
        for (int sp = 0; sp < 2; ++sp)
          a[oi][sp] = *(const bf16x8*)(WA + ((sp * 8 + kk) * 8 + wave * 2 + oi) * 512 + lane * 8);
#pragma unroll
      for (int st = 0; st < 8; ++st) {
        const short* hb = ffrag + kkl * 4096 + st * 512 + lane * 8;
        bf16x8 b0 = *(const bf16x8*)hb;
        bf16x8 b1 = *(const bf16x8*)(hb + 8192);
#pragma unroll
        for (int oi = 0; oi < 2; ++oi) {
          f32x4 c = acc[oi][st];
          c = __builtin_amdgcn_mfma_f32_16x16x32_bf16(a[oi][1], b0, c, 0, 0, 0);
          c = __builtin_amdgcn_mfma_f32_16x16x32_bf16(a[oi][0], b1, c, 0, 0, 0);
          c = __builtin_amdgcn_mfma_f32_16x16x32_bf16(a[oi][0], b0, c, 0, 0, 0);
          acc[oi][st] = c;
        }
      }
    }
    __syncthreads();
  }
#pragma unroll
  for (int oi = 0; oi < 2; ++oi) {
    int o0 = (wave * 2 + oi) * 16 + quad * 4;
    float4 bb = *(const float4*)&m1b[o0];
    float4 al = *(const float4*)&prep[o0];
#pragma unroll
    for (int st = 0; st < 8; ++st) {
      int m_out = m0 + st * 16 + nl;
      f32x4 cc = acc[oi][st];
      float4 r;
      r.x = (cc[0] + bb.x) * al.x;
      r.y = (cc[1] + bb.y) * al.y;
      r.z = (cc[2] + bb.z) * al.z;
      r.w = (cc[3] + bb.w) * al.w;
      *(float4*)&W1f[((size_t)(bk * 1024 + m_out)) * 128 + o0] = r;
    }
  }
}

// ---------------- MFMA GEMM over one 128(c) x nst_h*16(s) fragment buffer ----------
__device__ __forceinline__ void mfma_layer(const short* __restrict__ Wf,
                                           const short* hfrag, int l,
                                           int wave, int lane, int nst_h,
                                           f32x4 acc[2][4])
{
#pragma unroll 1
  for (int kk = 0; kk < 4; ++kk) {
    bf16x8 a[2][2];
#pragma unroll
    for (int oi = 0; oi < 2; ++oi)
#pragma unroll
      for (int sp = 0; sp < 2; ++sp)
        a[oi][sp] = *(const bf16x8*)(Wf + (((l * 2 + sp) * 4 + kk) * 8 + (wave * 2 + oi)) * 512 + lane * 8);
    for (int st = 0; st < nst_h; ++st) {
      const short* hb = hfrag + kk * 2048 + st * 512 + lane * 8;
      bf16x8 b0 = *(const bf16x8*)(hb);           // hi
      bf16x8 b1 = *(const bf16x8*)(hb + 8192);    // mid
#pragma unroll
      for (int oi = 0; oi < 2; ++oi) {
        f32x4 c = acc[oi][st];
        c = __builtin_amdgcn_mfma_f32_16x16x32_bf16(a[oi][1], b0, c, 0, 0, 0);
        c = __builtin_amdgcn_mfma_f32_16x16x32_bf16(a[oi][0], b1, c, 0, 0, 0);
        c = __builtin_amdgcn_mfma_f32_16x16x32_bf16(a[oi][0], b0, c, 0, 0, 0);
        acc[oi][st] = c;
      }
    }
  }
}

// ---------------- fused SA: 4 balls per block, tiles packed over passes ----------
// Tile q covers 16 samples of one ball; padded bidx slots replicate a real sample,
// so per-tile max == per-ball max contribution (fmax is order-insensitive).
__global__ __launch_bounds__(256, 3) void sa_kernel(
    const float* __restrict__ xc, const float* __restrict__ nxyz,
    const int* __restrict__ bidx, const int* __restrict__ counts,
    const float* __restrict__ W1f, const float* __restrict__ prep,
    const short* __restrict__ Wf, float* __restrict__ feat_out)
{
  __shared__ __align__(16) short hfrag[16384];   // 32KB: 2 splits x 128c x 64s frags
  __shared__ float pcs[512];                     // layer-1 xyz consts {w0,w1,w2,be}*128
  __shared__ float sm[32 * 128];                 // 16KB per-tile o-max
  __shared__ float ccen[12];
  __shared__ int scnt[4];
  int gb = blockIdx.x, bk = gb >> 5, pb = (gb & 31) << 2;
  int t = threadIdx.x;
  int wave = t >> 6, lane = t & 63;
  int quad = lane >> 4, nl = lane & 15;

  pcs[t] = prep[1280 + t];
  pcs[256 + t] = prep[1536 + t];
  if (t < 4) scnt[t] = counts[bk * 128 + pb + t];
  if (t < 12) ccen[t] = nxyz[(bk * 128 + pb + (t >> 2) % 4) * 3 + 0];   // placeholder
  __syncthreads();
  if (t < 12) {
    int bb = t / 3, c = t % 3;
    ccen[t] = nxyz[(bk * 128 + pb + bb) * 3 + c];
  }
  int n0 = (scnt[0] + 15) >> 4, n1 = (scnt[1] + 15) >> 4;
  int n2 = (scnt[2] + 15) >> 4, n3 = (scnt[3] + 15) >> 4;
  int pf1 = n0, pf2 = n0 + n1, pf3 = n0 + n1 + n2, T = n0 + n1 + n2 + n3;
  __syncthreads();

  for (int q0 = 0; q0 < T; q0 += 4) {
    int nst_h = T - q0;
    if (nst_h > 4) nst_h = 4;
    // ---- h1 build ----
    {
      int cg = wave;
      int st = lane >> 4, sl = lane & 15;
      if (st < nst_h) {
        int q = q0 + st;
        int bq = (q >= pf1) + (q >= pf2) + (q >= pf3);
        int tstart = (bq == 0) ? 0 : (bq == 1) ? pf1 : (bq == 2) ? pf2 : pf3;
        int tslot = q - tstart;
        int m = bidx[((size_t)(bk * 128 + pb + bq)) * 128 + tslot * 16 + sl];
        float cen0 = ccen[bq * 3 + 0], cen1 = ccen[bq * 3 + 1], cen2 = ccen[bq * 3 + 2];
        float g0 = (xc[(bk * 3 + 0) * 1024 + m] - cen0) * (1.0f / 0.15f);
        float g1 = (xc[(bk * 3 + 1) * 1024 + m] - cen1) * (1.0f / 0.15f);
        float g2 = (xc[(bk * 3 + 2) * 1024 + m] - cen2) * (1.0f / 0.15f);
        const float4* wrow = (const float4*)(W1f + ((size_t)(bk * 1024 + m)) * 128 + cg * 32);
        const float4* pcp = (const float4*)pcs + cg * 32;
#pragma unroll
        for (int g = 0; g < 4; ++g) {
          float4 wva = wrow[g * 2], wvb = wrow[g * 2 + 1];
          float wv[8] = {wva.x, wva.y, wva.z, wva.w, wvb.x, wvb.y, wvb.z, wvb.w};
          unsigned sh[8], smv[8];
#pragma unroll
          for (int e = 0; e < 8; ++e) {
            float4 pc = pcp[g * 8 + e];
            float hv = fmaxf(wv[e] + pc.x * g0 + pc.y * g1 + pc.z * g2 + pc.w, 0.f);
            split2rn(hv, sh[e], smv[e]);
          }
          int base = (cg * 4 + st) * 512 + (g * 16 + sl) * 8;
          v4i ph = {(int)(sh[0] | (sh[1] << 16)), (int)(sh[2] | (sh[3] << 16)),
                    (int)(sh[4] | (sh[5] << 16)), (int)(sh[6] | (sh[7] << 16))};
          *(v4i*)&hfrag[base] = ph;
          v4i pm = {(int)(smv[0] | (smv[1] << 16)), (int)(smv[2] | (smv[3] << 16)),
                    (int)(smv[4] | (smv[5] << 16)), (int)(smv[6] | (smv[7] << 16))};
          *(v4i*)&hfrag[base + 8192] = pm;
        }
      }
    }
    __syncthreads();

    // ---- layer 2 (l=0) ----
    f32x4 acc[2][4];
#pragma unroll
    for (int oi = 0; oi < 2; ++oi)
#pragma unroll
      for (int st = 0; st < 4; ++st) acc[oi][st] = (f32x4){0.f, 0.f, 0.f, 0.f};
    mfma_layer(Wf, hfrag, 0, wave, lane, nst_h, acc);
    __syncthreads();

    // ---- h2 epilogue: BN+ReLU, split2, write back as fragments ----
#pragma unroll
    for (int oi = 0; oi < 2; ++oi) {
      int o0 = (wave * 2 + oi) * 16 + quad * 4;
      float4 al = *(const float4*)&prep[256 + o0];
      float4 be = *(const float4*)&prep[384 + o0];
      int kk2 = o0 >> 5, g2 = (o0 & 31) >> 3, j0 = o0 & 7;    // j0 in {0,4}
      for (int st = 0; st < nst_h; ++st) {
        f32x4 cc = acc[oi][st];
        float v0 = fmaxf(fmaf(cc[0], al.x, be.x), 0.f);
        float v1 = fmaxf(fmaf(cc[1], al.y, be.y), 0.f);
        float v2 = fmaxf(fmaf(cc[2], al.z, be.z), 0.f);
        float v3 = fmaxf(fmaf(cc[3], al.w, be.w), 0.f);
        unsigned h0, m0_, h1, m1_, h2, m2_, h3, m3_;
        split2rn(v0, h0, m0_); split2rn(v1, h1, m1_);
        split2rn(v2, h2, m2_); split2rn(v3, h3, m3_);
        int base = (kk2 * 4 + st) * 512 + (g2 * 16 + nl) * 8 + j0;
        v2i w0 = {(int)(h0 | (h1 << 16)), (int)(h2 | (h3 << 16))};
        *(v2i*)&hfrag[base] = w0;
        v2i w1 = {(int)(m0_ | (m1_ << 16)), (int)(m2_ | (m3_ << 16))};
        *(v2i*)&hfrag[base + 8192] = w1;
      }
    }
    __syncthreads();

    // ---- layer 3 (l=1) ----
#pragma unroll
    for (int oi = 0; oi < 2; ++oi)
#pragma unroll
      for (int st = 0; st < 4; ++st) acc[oi][st] = (f32x4){0.f, 0.f, 0.f, 0.f};
    mfma_layer(Wf, hfrag, 1, wave, lane, nst_h, acc);

    // ---- layer-3 epilogue: BN+ReLU, quad-reduce max per tile, store to sm ----
#pragma unroll
    for (int oi = 0; oi < 2; ++oi) {
      int o0 = (wave * 2 + oi) * 16 + quad * 4;
      float4 al = *(const float4*)&prep[512 + o0];
      float4 be = *(const float4*)&prep[640 + o0];
      for (int st = 0; st < nst_h; ++st) {
        f32x4 cc = acc[oi][st];
        float v[4];
        v[0] = fmaxf(fmaf(cc[0], al.x, be.x), 0.f);
        v[1] = fmaxf(fmaf(cc[1], al.y, be.y), 0.f);
        v[2] = fmaxf(fmaf(cc[2], al.z, be.z), 0.f);
        v[3] = fmaxf(fmaf(cc[3], al.w, be.w), 0.f);
#pragma unroll
        for (int r = 0; r < 4; ++r) {
          float x = v[r];
          x = fmaxf(x, __shfl_xor(x, 1));
          x = fmaxf(x, __shfl_xor(x, 2));
          x = fmaxf(x, __shfl_xor(x, 4));
          x = fmaxf(x, __shfl_xor(x, 8));
          if (nl == 0) sm[(q0 + st) * 128 + o0 + r] = x;
        }
      }
    }
    __syncthreads();                              // hfrag reads done before next pass
  }

  // ---- final: merge tiles per ball, write feat ----
#pragma unroll
  for (int e = t; e < 512; e += 256) {
    int bb = e >> 7, o = e & 127;
    int qs = (bb == 0) ? 0 : (bb == 1) ? pf1 : (bb == 2) ? pf2 : pf3;
    int nq = (bb == 0) ? n0 : (bb == 1) ? n1 : (bb == 2) ? n2 : n3;
    float v = sm[qs * 128 + o];
    for (int q = 1; q < nq; ++q) v = fmaxf(v, sm[(qs + q) * 128 + o]);
    feat_out[(((size_t)bk) << 14) + (o << 7) + pb + bb] = v;
  }
}

// 8x8 register-tile GEMM over a 128x128 LDS operand; w is [c][o] in global
__device__ __forceinline__ void gemm_tile(const float* __restrict__ w,
                                          const float* lds, int tx, int ty,
                                          float acc[8][8])
{
#pragma unroll
  for (int i = 0; i < 8; ++i)
#pragma unroll
    for (int j = 0; j < 8; ++j) acc[i][j] = 0.f;
  for (int c = 0; c < 128; ++c) {
    const float4* wr = (const float4*)(w + c * 128 + ty * 8);
    float4 a0 = wr[0], a1 = wr[1];
    const float4* hr = (const float4*)(lds + c * 128 + tx * 8);
    float4 b0 = hr[0], b1 = hr[1];
    float av[8] = {a0.x, a0.y, a0.z, a0.w, a1.x, a1.y, a1.z, a1.w};
    float bv[8] = {b0.x, b0.y, b0.z, b0.w, b1.x, b1.y, b1.z, b1.w};
#pragma unroll
    for (int i = 0; i < 8; ++i)
#pragma unroll
      for (int j = 0; j < 8; ++j) acc[i][j] = fmaf(av[i], bv[j], acc[i][j]);
  }
}

// ---------------- head: c1 -> c2 -> op -> scores ----------------
__global__ __launch_bounds__(256) void head_kernel(const float* __restrict__ featg,
    const float* __restrict__ prep, const float* __restrict__ wt,
    const float* __restrict__ nxyz, const float* __restrict__ opw,
    const float* __restrict__ opb, float* __restrict__ scores)
{
  __shared__ __align__(16) float buf[128 * 128];
  int bk = blockIdx.x, t = threadIdx.x;
  for (int i = t; i < 16384; i += 256) buf[i] = featg[(bk << 14) + i];
  __syncthreads();
  int tx = t & 15, ty = t >> 4;
  float acc[8][8];

  // c1
  gemm_tile(wt, buf, tx, ty, acc);
  __syncthreads();
#pragma unroll
  for (int i = 0; i < 8; ++i) {
    int o = ty * 8 + i;
    float al = prep[768 + o], be = prep[896 + o];
#pragma unroll
    for (int j = 0; j < 8; ++j)
      buf[o * 128 + tx * 8 + j] = fmaxf(fmaf(acc[i][j], al, be), 0.f);
  }
  __syncthreads();

  // c2
  gemm_tile(wt + 16384, buf, tx, ty, acc);
  __syncthreads();
#pragma unroll
  for (int i = 0; i < 8; ++i) {
    int o = ty * 8 + i;
    float al = prep[1024 + o], be = prep[1152 + o];
#pragma unroll
    for (int j = 0; j < 8; ++j)
      buf[o * 128 + tx * 8 + j] = fmaxf(fmaf(acc[i][j], al, be), 0.f);
  }
  __syncthreads();

  // op head + scores assembly
  if (t < 128) {
    int p = t, k = bk % 19;
    float res[5];
#pragma unroll
    for (int j = 0; j < 5; ++j) {
      const float* wr = opw + ((size_t)(k * 5 + j)) * 128;
      float a = opb[k * 5 + j];
      for (int c = 0; c < 128; ++c) a = fmaf(wr[c], buf[c * 128 + p], a);
      res[j] = a;
    }
    float a0 = nxyz[(bk * 128 + p) * 3 + 0];
    float a1 = nxyz[(bk * 128 + p) * 3 + 1];
    float a2 = nxyz[(bk * 128 + p) * 3 + 2];
    float* sc = scores + ((size_t)(bk * 128 + p)) * 5;
    sc[0] = res[0];
    sc[1] = res[1];
    sc[2] = a0 + res[2];
    sc[3] = a1 + res[3];
    sc[4] = a2 + res[4];
  }
}

extern "C" void kernel_launch(void* const* d_in, const int* in_sizes, int n_in,
                              void* d_out, int out_size, void* d_ws, size_t ws_size,
                              hipStream_t stream) {
  (void)in_sizes; (void)n_in; (void)out_size; (void)ws_size;
  const float* xyz  = (const float*)d_in[0];
  const float* fts  = (const float*)d_in[1];
  const float* m1w  = (const float*)d_in[2];
  const float* m1b  = (const float*)d_in[3];
  const float* m1g  = (const float*)d_in[4];
  const float* m1be = (const float*)d_in[5];
  const float* m2w  = (const float*)d_in[6];
  const float* m2b  = (const float*)d_in[7];
  const float* m2g  = (const float*)d_in[8];
  const float* m2be = (const float*)d_in[9];
  const float* m3w  = (const float*)d_in[10];
  const float* m3b  = (const float*)d_in[11];
  const float* m3g  = (const float*)d_in[12];
  const float* m3be = (const float*)d_in[13];
  const float* c1w  = (const float*)d_in[14];
  const float* c1b  = (const float*)d_in[15];
  const float* c1g  = (const float*)d_in[16];
  const float* c1be = (const float*)d_in[17];
  const float* c2w  = (const float*)d_in[18];
  const float* c2b  = (const float*)d_in[19];
  const float* c2g  = (const float*)d_in[20];
  const float* c2be = (const float*)d_in[21];
  const float* opw  = (const float*)d_in[22];
  const float* opb  = (const float*)d_in[23];

  float* out = (float*)d_out;
  char* ws = (char*)d_ws;
  float* xc   = (float*)(ws + OFF_XC);
  float* nxyz = (float*)(ws + OFF_NXYZ);
  int*   bidx = (int*)(ws + OFF_BIDX);
  float* W1f  = (float*)(ws + OFF_W1F);
  float* prep = (float*)(ws + OFF_PREP);
  float* wt   = (float*)(ws + OFF_WT);
  short* Wf   = (short*)(ws + OFF_WF);
  int*   cnt  = (int*)(ws + OFF_CNT);

  hipLaunchKernelGGL(prep_kernel, dim3(1), dim3(256), 0, stream,
                     m1w, m1g, m1be, m2b, m2g, m2be, m3b, m3g, m3be,
                     c1b, c1g, c1be, c2b, c2g, c2be, prep);
  hipLaunchKernelGGL(wsplit_kernel, dim3(64), dim3(256), 0, stream,
                     m1w, m2w, m3w, c1w, c2w, Wf, wt);
  hipLaunchKernelGGL(fps_kernel, dim3(NBK), dim3(256), 0, stream,
                     xyz, xc, nxyz, out + OUT_AGG);
  hipLaunchKernelGGL(ball_kernel, dim3(NBK * 128), dim3(64), 0, stream,
                     xc, nxyz, bidx, cnt);
  hipLaunchKernelGGL(w1f_kernel, dim3(NBK * 8), dim3(256), 0, stream,
                     fts, m1b, prep, Wf, W1f);
  hipLaunchKernelGGL(sa_kernel, dim3(NBK * 32), dim3(256), 0, stream,
                     xc, nxyz, bidx, cnt, W1f, prep, Wf, out + OUT_FEAT);
  hipLaunchKernelGGL(head_kernel, dim3(NBK), dim3(256), 0, stream,
                     out + OUT_FEAT, prep, wt, nxyz, opw, opb, out);
}